// Round 1
// 778.878 us; speedup vs baseline: 1.8412x; 1.8412x over previous
//
#include <hip/hip_runtime.h>
#include <stdint.h>

#define T_STEPS 1024
#define BATCH   512
#define IN_DIM  64
#define HID_DIM 256
#define OUT_DIM 32

// ===========================================================================
// NUMERICS CONTRACT (validated by R4 pass, absmax 7.8e-3 vs 5.75e-2):
//   * dot products: single fp32 accumulator, k ASCENDING, fmaf each step
//   * bias: separately-rounded fp32 add AFTER the chain
//   * LIF: mem = ((0.92f*mem) + cur) - reset, three separate fp32 ops,
//          reset from PREVIOUS mem, compares mem > 1.0f
// Any reassociation flips spikes (binary outputs, 16.7M decisions). Do not.
// Interleaving two t-steps' chains below does NOT reassociate: each acc is
// still its own single-accumulator ascending chain.
// ===========================================================================

#define GLOAD_LDS16(GP, LP)                                                \
    __builtin_amdgcn_global_load_lds(                                      \
        (const __attribute__((address_space(1))) void*)(GP),               \
        (__attribute__((address_space(3))) void*)(LP), 16, 0, 0)

// ---------------------------------------------------------------------------
// Phase 1: fused GEMM1 + LIF1. Block = one batch b, thread = h; t sequential.
// v2 changes vs 1434us baseline:
//   * W1 row pinned in VGPRs via empty asm (compiler had sunk the loads into
//     the t-loop: VGPR_Count was 40 < 64 -> 256 B of W1 reloaded every step).
//   * x staged through LDS in 32-step chunks, double-buffered, via
//     global_load_lds width=16 -> prefetch depth 32 steps instead of 1, so
//     ~900cy HBM latency hides under ~6000cy of compute. One barrier/chunk.
//   * two t-steps' FMA chains interleaved (acc0/acc1) for dep-latency ILP
//     (only 2 waves/SIMD exist; ILP must cover the 4cy fmac latency).
// ---------------------------------------------------------------------------
#define CHUNK 32

__global__ __launch_bounds__(256, 2) void snn_l1(
    const float* __restrict__ x,                  // [T,B,64]
    const float* __restrict__ W1,                 // [256,64]
    const float* __restrict__ b1,                 // [256]
    unsigned long long* __restrict__ bits)        // [T,B,4] u64 ballots
{
    const int b    = blockIdx.x;
    const int h    = threadIdx.x;
    const int wv   = h >> 6;
    const int lane = h & 63;

    __shared__ __align__(16) float xs[2][CHUNK][IN_DIM];   // 2 x 8 KB

    float w1r[IN_DIM];
#pragma unroll
    for (int k = 0; k < IN_DIM; ++k) w1r[k] = W1[h * IN_DIM + k];
    // Pin the row in VGPRs: each asm consumes the loaded value, so the loads
    // cannot be sunk into the t-loop (the VGPR=40 bug of the prior version).
#pragma unroll
    for (int k = 0; k < IN_DIM; ++k) asm volatile("" : "+v"(w1r[k]));
    const float bias1 = b1[h];

    // Staging geometry: one buffer = CHUNK*64 floats = 512 float4 slots.
    // Thread covers slots (r*4+wv)*64+lane, r=0..1. LDS dest is linear
    // (wave-uniform base + lane*16) as global_load_lds requires; global
    // source address is per-lane (rows of x are 256 B, strided B*256 B).
#define STAGE(BUF, CT)                                                     \
    {                                                                      \
        _Pragma("unroll")                                                  \
        for (int r = 0; r < 2; ++r) {                                      \
            const int slot = (r * 4 + wv) * 64 + lane;                     \
            const int step = slot >> 4;                                    \
            const int f4   = slot & 15;                                    \
            const float4* gp = (const float4*)x +                          \
                ((size_t)((CT) * CHUNK + step) * BATCH + b) * 16 + f4;     \
            GLOAD_LDS16(gp, &xs[BUF][0][0] + slot * 4);                    \
        }                                                                  \
    }

    float mem1 = 0.0f;

    STAGE(0, 0)

    for (int c = 0; c < T_STEPS / CHUNK; ++c) {
        const int cb = c & 1;
        // Drains each wave's own global_load_lds (vmcnt) then barriers:
        // buf[cb] is fully staged, and every wave is done reading buf[cb^1].
        __syncthreads();
        if (c + 1 < T_STEPS / CHUNK) STAGE(cb ^ 1, c + 1)

#pragma unroll
        for (int s = 0; s < CHUNK; s += 2) {
            const float4* xp0 = (const float4*)(&xs[cb][s][0]);
            const float4* xp1 = (const float4*)(&xs[cb][s + 1][0]);
            float acc0 = 0.0f, acc1 = 0.0f;
#pragma unroll
            for (int i = 0; i < 16; ++i) {
                const float4 u = xp0[i];        // broadcast ds_read_b128
                const float4 v = xp1[i];
                acc0 = fmaf(u.x, w1r[4 * i + 0], acc0);
                acc0 = fmaf(u.y, w1r[4 * i + 1], acc0);
                acc0 = fmaf(u.z, w1r[4 * i + 2], acc0);
                acc0 = fmaf(u.w, w1r[4 * i + 3], acc0);
                acc1 = fmaf(v.x, w1r[4 * i + 0], acc1);
                acc1 = fmaf(v.y, w1r[4 * i + 1], acc1);
                acc1 = fmaf(v.z, w1r[4 * i + 2], acc1);
                acc1 = fmaf(v.w, w1r[4 * i + 3], acc1);
            }
            const int t0 = c * CHUNK + s;
            {
                const float cur1 = __fadd_rn(acc0, bias1);
                const float r1 = (mem1 > 1.0f) ? 1.0f : 0.0f;
                mem1 = __fsub_rn(__fadd_rn(__fmul_rn(0.92f, mem1), cur1), r1);
                const unsigned long long bm = __ballot(mem1 > 1.0f);
                if (lane == 0)
                    bits[((size_t)t0 * BATCH + b) * 4 + wv] = bm;
            }
            {
                const float cur1 = __fadd_rn(acc1, bias1);
                const float r1 = (mem1 > 1.0f) ? 1.0f : 0.0f;
                mem1 = __fsub_rn(__fadd_rn(__fmul_rn(0.92f, mem1), cur1), r1);
                const unsigned long long bm = __ballot(mem1 > 1.0f);
                if (lane == 0)
                    bits[((size_t)(t0 + 1) * BATCH + b) * 4 + wv] = bm;
            }
        }
    }
#undef STAGE
}

// ---------------------------------------------------------------------------
// Phase 2: GEMM2 over all (t,b,o) in parallel. Lane = one (t,b), 4 outputs
// o = og*4..og*4+3 (og = blockIdx.y, wave-uniform -> W2 rows via scalar
// loads). Spikes as 8 u32 bit-words per lane; per k: bfe + cvt + 4 fmac.
// Exact k-ascending chain per output preserved. Stores cur2 (+bias).
// ---------------------------------------------------------------------------
__global__ __launch_bounds__(256, 4) void snn_l2gemm(
    const uint32_t* __restrict__ bits,   // [T*B, 8] u32
    const float* __restrict__ W2,        // [32,256]
    const float* __restrict__ b2,        // [32]
    float* __restrict__ cur2)            // [T*B, 32]
{
    const int    og = blockIdx.y;                              // 0..7
    const size_t tb = (size_t)blockIdx.x * 256 + threadIdx.x;  // 0..T*B-1

    const uint4 wA = ((const uint4*)bits)[tb * 2 + 0];
    const uint4 wB = ((const uint4*)bits)[tb * 2 + 1];
    const uint32_t wds[8] = {wA.x, wA.y, wA.z, wA.w, wB.x, wB.y, wB.z, wB.w};

    const float* __restrict__ wr0 = W2 + (og * 4 + 0) * HID_DIM;
    const float* __restrict__ wr1 = W2 + (og * 4 + 1) * HID_DIM;
    const float* __restrict__ wr2 = W2 + (og * 4 + 2) * HID_DIM;
    const float* __restrict__ wr3 = W2 + (og * 4 + 3) * HID_DIM;

    float a0 = 0.0f, a1 = 0.0f, a2 = 0.0f, a3 = 0.0f;

#pragma unroll
    for (int c = 0; c < 16; ++c) {            // 16 chunks x 16 k
        float r0[16], r1[16], r2[16], r3[16];
#pragma unroll
        for (int i = 0; i < 16; ++i) {
            const int k = c * 16 + i;
            r0[i] = wr0[k];                   // wave-uniform -> s_load
            r1[i] = wr1[k];
            r2[i] = wr2[k];
            r3[i] = wr3[k];
        }
        const uint32_t word = wds[c >> 1];
        const int      base = (c & 1) * 16;
#pragma unroll
        for (int i = 0; i < 16; ++i) {
            const float sf = (float)((word >> (base + i)) & 1u);  // 0.0 / 1.0
            a0 = fmaf(sf, r0[i], a0);         // exact: == fl(acc + w) or acc
            a1 = fmaf(sf, r1[i], a1);
            a2 = fmaf(sf, r2[i], a2);
            a3 = fmaf(sf, r3[i], a3);
        }
    }

    a0 = __fadd_rn(a0, b2[og * 4 + 0]);       // separately-rounded bias add
    a1 = __fadd_rn(a1, b2[og * 4 + 1]);
    a2 = __fadd_rn(a2, b2[og * 4 + 2]);
    a3 = __fadd_rn(a3, b2[og * 4 + 3]);

    ((float4*)cur2)[tb * (OUT_DIM / 4) + og] = make_float4(a0, a1, a2, a3);
}

// ---------------------------------------------------------------------------
// Phase 3: LIF2 t-scan. Thread = (b,o), 16384 chains. Reads cur2 in-place
// from the out_spk region and overwrites it with spk2; mem2 to out_mem
// (which also overwrites the by-now-consumed bits scratch). 8-deep load
// batching to keep HBM/L3 requests in flight.
// ---------------------------------------------------------------------------
__global__ __launch_bounds__(256, 4) void snn_l2scan(
    float* __restrict__ spk_io,          // [T,B,32]: cur2 in, spk2 out
    float* __restrict__ mem_out)         // [T,B,32]
{
    const int tid = threadIdx.x;
    const int o   = tid & (OUT_DIM - 1);
    const int b   = blockIdx.x * 8 + (tid >> 5);

    float* p = spk_io  + (size_t)b * OUT_DIM + o;
    float* m = mem_out + (size_t)b * OUT_DIM + o;
    const size_t step = (size_t)BATCH * OUT_DIM;

    float mem2 = 0.0f;
    for (int t = 0; t < T_STEPS; t += 8) {
        float c[8];
#pragma unroll
        for (int u = 0; u < 8; ++u) c[u] = p[(size_t)(t + u) * step];
#pragma unroll
        for (int u = 0; u < 8; ++u) {
            const float r2 = (mem2 > 1.0f) ? 1.0f : 0.0f;
            mem2 = __fsub_rn(__fadd_rn(__fmul_rn(0.92f, mem2), c[u]), r2);
            p[(size_t)(t + u) * step] = (mem2 > 1.0f) ? 1.0f : 0.0f;
            m[(size_t)(t + u) * step] = mem2;
        }
    }
}

extern "C" void kernel_launch(void* const* d_in, const int* in_sizes, int n_in,
                              void* d_out, int out_size, void* d_ws, size_t ws_size,
                              hipStream_t stream) {
    const float* x  = (const float*)d_in[0];  // [T,B,64] fp32
    const float* W1 = (const float*)d_in[1];  // [256,64] fp32
    const float* b1 = (const float*)d_in[2];  // [256]    fp32
    const float* W2 = (const float*)d_in[3];  // [32,256] fp32
    const float* b2 = (const float*)d_in[4];  // [32]     fp32

    float* out_spk = (float*)d_out;                                  // 67 MB
    float* out_mem = out_spk + (size_t)T_STEPS * BATCH * OUT_DIM;    // 67 MB

    // Scratch plan (zero d_ws usage):
    //   bits (16 MB) live at the start of out_mem; consumed entirely by
    //   phase 2 before phase 3 overwrites that region with mem2.
    //   cur2 lives in out_spk; phase 3 overwrites it in-place with spk2.
    unsigned long long* bits = (unsigned long long*)out_mem;

    snn_l1<<<BATCH, 256, 0, stream>>>(x, W1, b1, bits);

    dim3 g2(T_STEPS * BATCH / 256, 8);
    snn_l2gemm<<<g2, 256, 0, stream>>>((const uint32_t*)bits, W2, b2, out_spk);

    snn_l2scan<<<BATCH / 8, 256, 0, stream>>>(out_spk, out_mem);
}